// Round 9
// baseline (10627.794 us; speedup 1.0000x reference)
//
#include <hip/hip_runtime.h>

// ---------------------------------------------------------------------------
// 2-layer LSTM (B=256,T=1024,in=64,H=128) + fused FC(128->32), bf16 MFMA.
// R9: R=1 batch row per block, 512 blocks (256 L0 + 256 L1) -> 2 blocks/CU,
// 4 waves/SIMD from two UNSYNCHRONIZED blocks: block B issues while block A
// stalls on its recurrence chain. Structure otherwise identical to R6
// (766us): LDS x-staging + 2-step reg prefetch, accX one-step-ahead split,
// layer pipeline via out0 + agent-scope flags (CH=16, lag 2 chunks).
// __launch_bounds__(512,4) pins VGPR<=128 so 16 waves/CU co-reside.
// ---------------------------------------------------------------------------

static constexpr int B   = 256;
static constexpr int T   = 1024;
static constexpr int H   = 128;
static constexpr int O   = 32;
static constexpr int NBL = 256;       // blocks per layer (1 batch row each)
static constexpr int CH  = 16;        // steps per pipeline chunk
static constexpr int NCH = T / CH;

typedef __attribute__((ext_vector_type(8))) short  short8;
typedef __attribute__((ext_vector_type(4))) float  f32x4;

#define LOG2E 1.4426950408889634f

#if __has_builtin(__builtin_amdgcn_exp2f)
#define EXP2(x) __builtin_amdgcn_exp2f(x)
#else
#define EXP2(x) __expf((x) * 0.69314718056f)
#endif
#if __has_builtin(__builtin_amdgcn_rcpf)
#define RCP(x) __builtin_amdgcn_rcpf(x)
#else
#define RCP(x) (1.0f / (x))
#endif

__device__ __forceinline__ unsigned short f2bf(float f) {
  unsigned int u = __builtin_bit_cast(unsigned int, f);
  u += 0x7fffu + ((u >> 16) & 1u);        // round-to-nearest-even
  return (unsigned short)(u >> 16);
}

__device__ __forceinline__ float sigm(float x) {
  return RCP(1.0f + EXP2(-LOG2E * x));
}
__device__ __forceinline__ float tanh_f(float x) {
  return 1.0f - 2.0f * RCP(1.0f + EXP2(2.0f * LOG2E * x));
}

// LDS-only barrier: wait own ds ops, then s_barrier. Global ops float.
__device__ __forceinline__ void block_sync_lds() {
  __builtin_amdgcn_sched_barrier(0);
  asm volatile("s_waitcnt lgkmcnt(0)" ::: "memory");
  __builtin_amdgcn_s_barrier();
  __builtin_amdgcn_sched_barrier(0);
}

// ---------------------------------------------------------------------------
// One layer's full-T scan for ONE batch row. 8 waves; wave w owns gate cols
// [w*16,w*16+16) of each gate block (i,f,g,o). Lane with lhi==0 owns the row
// (tile row 0, acc reg 0). LDS A[buf] at iter t holds {h(t-1), x(t+1)};
// accX = bias + x@Wih computed one step ahead; gates = mfma(h, Whh, C=accX).
// ---------------------------------------------------------------------------
template <int KIN, bool IN_BF16, bool WRITE_HOUT, bool FUSE_FC, bool PROD, bool CONS>
__device__ __forceinline__ void scan_body(
    unsigned short* __restrict__ Ash,
    const void* __restrict__ in_,            // [B,T,KIN] f32 (L0) / bf16 (L1)
    const float* __restrict__ h0,            // [B,H] layer slice
    const float* __restrict__ c0,            // [B,H] layer slice
    const float* __restrict__ Wih,           // [4H,KIN]
    const float* __restrict__ Whh,           // [4H,H]
    const float* __restrict__ bih,           // [4H]
    const float* __restrict__ bhh,           // [4H]
    unsigned short* __restrict__ hout,       // bf16 [B,T,H] (L0 only)
    float* __restrict__ hN,                  // [B,H]
    float* __restrict__ cN,                  // [B,H]
    const float* __restrict__ Wfc,           // [32,128] (L1 only)
    const float* __restrict__ bfc,           // [32]
    float* __restrict__ fco,                 // [B,T,32]
    int* __restrict__ flag, const int bbase) // bbase = batch row
{
  constexpr int AK   = KIN + H;              // 192 or 256
  constexpr int KCX  = KIN / 32;             // 2 or 4
  constexpr int KCH  = H / 32;               // 4
  constexpr int APAD = AK + 8;               // 16B-multiple row stride

  const int tid  = threadIdx.x;
  const int w    = tid >> 6;
  const int l    = tid & 63;
  const int l15  = l & 15;
  const int lhi  = l >> 4;
  const int jcol = w * 16 + l15;
  const bool own = (lhi == 0);               // lane owns the single row

#define AEL(buf, row, col) Ash[(((buf) * 16 + (row)) * APAD) + (col)]

  // ---- gate-weight fragments, split x-part / h-part ----
  short8 wfx[4][KCX], wfh[4][KCH];
  float  bias4[4];
#pragma unroll
  for (int gb = 0; gb < 4; ++gb) {
    const int gc = gb * H + jcol;
    const float* wi = Wih + (size_t)gc * KIN;
    const float* wh = Whh + (size_t)gc * H;
#pragma unroll
    for (int kc = 0; kc < KCX; ++kc) {
      const float* s = wi + kc * 32 + lhi * 8;
      float4 a = *(const float4*)s;
      float4 b = *(const float4*)(s + 4);
      short8 v;
      v[0] = (short)f2bf(a.x); v[1] = (short)f2bf(a.y);
      v[2] = (short)f2bf(a.z); v[3] = (short)f2bf(a.w);
      v[4] = (short)f2bf(b.x); v[5] = (short)f2bf(b.y);
      v[6] = (short)f2bf(b.z); v[7] = (short)f2bf(b.w);
      wfx[gb][kc] = v;
    }
#pragma unroll
    for (int kc = 0; kc < KCH; ++kc) {
      const float* s = wh + kc * 32 + lhi * 8;
      float4 a = *(const float4*)s;
      float4 b = *(const float4*)(s + 4);
      short8 v;
      v[0] = (short)f2bf(a.x); v[1] = (short)f2bf(a.y);
      v[2] = (short)f2bf(a.z); v[3] = (short)f2bf(a.w);
      v[4] = (short)f2bf(b.x); v[5] = (short)f2bf(b.y);
      v[6] = (short)f2bf(b.z); v[7] = (short)f2bf(b.w);
      wfh[gb][kc] = v;
    }
    bias4[gb] = bih[gc] + bhh[gc];
  }

  // ---- FC weight fragments (waves 0,1) ----
  short8 bfr[4];
  float fcbias = 0.f;
  if constexpr (FUSE_FC) {
    const int oc = (w & 1) * 16 + l15;
#pragma unroll
    for (int kc = 0; kc < 4; ++kc) {
      const float* s = Wfc + (size_t)oc * H + kc * 32 + lhi * 8;
      float4 a = *(const float4*)s;
      float4 b = *(const float4*)(s + 4);
      short8 v;
      v[0] = (short)f2bf(a.x); v[1] = (short)f2bf(a.y);
      v[2] = (short)f2bf(a.z); v[3] = (short)f2bf(a.w);
      v[4] = (short)f2bf(b.x); v[5] = (short)f2bf(b.y);
      v[6] = (short)f2bf(b.z); v[7] = (short)f2bf(b.w);
      bfr[kc] = v;
    }
    fcbias = bfc[oc];
  }

  // lane lhi==0 owns the batch row (tile row 0, acc reg 0)
  float cst   = own ? c0[(size_t)bbase * H + jcol] : 0.f;
  float hlast = 0.f;

  const float*          inf = (const float*)in_;
  const unsigned short* inb = (const unsigned short*)in_;

  // staging coords: 32 lanes cover the single row's KIN elements
  const bool sact = tid < 32;
  int scol;
  if constexpr (!IN_BF16) scol = (tid * 2) & 63;
  else                    scol = (tid * 4) & 127;
  const float*          xpf = inf + (size_t)bbase * T * KIN + scol;
  const unsigned short* xpb = inb + (size_t)bbase * T * KIN + scol;

  unsigned short* hp = nullptr;
  if constexpr (WRITE_HOUT)
    hp = hout + (size_t)bbase * T * H + jcol;
  float* fp = nullptr;
  if constexpr (FUSE_FC)
    fp = fco + (size_t)bbase * T * O + (w & 1) * 16 + l15;

  // ---- zero both A buffers once (padding rows stay 0 forever) ----
  for (int i = tid; i < 16 * APAD; i += 512)
    ((unsigned int*)Ash)[i] = 0u;
  __syncthreads();

  // ---- consumer: wait for chunks 0,1 before touching in_ ----
  if constexpr (CONS) {
    if (tid == 0) {
      while (__hip_atomic_load(flag, __ATOMIC_ACQUIRE, __HIP_MEMORY_SCOPE_AGENT) < 2)
        __builtin_amdgcn_s_sleep(4);
    }
    __syncthreads();
  }

  // ---- prologue ----
  // A[1].x <- x(0) (consumed below for accX_0);  A[0].x <- x(1);  A[0].h <- h0
  if (sact) {
    if constexpr (!IN_BF16) {
      float2 v0 = *(const float2*)xpf;
      float2 v1 = *(const float2*)(xpf + KIN);
      *(unsigned int*)&AEL(1, 0, scol) =
          (unsigned int)f2bf(v0.x) | ((unsigned int)f2bf(v0.y) << 16);
      *(unsigned int*)&AEL(0, 0, scol) =
          (unsigned int)f2bf(v1.x) | ((unsigned int)f2bf(v1.y) << 16);
    } else {
      uint2 v0 = *(const uint2*)xpb;
      uint2 v1 = *(const uint2*)(xpb + KIN);
      *(uint2*)&AEL(1, 0, scol) = v0;
      *(uint2*)&AEL(0, 0, scol) = v1;
    }
  }
  if (tid < 32) {
    const int col = tid * 4;
    float4 v = *(const float4*)(h0 + (size_t)bbase * H + col);
    uint2 p;
    p.x = (unsigned int)f2bf(v.x) | ((unsigned int)f2bf(v.y) << 16);
    p.y = (unsigned int)f2bf(v.z) | ((unsigned int)f2bf(v.w) << 16);
    *(uint2*)&AEL(0, 0, KIN + col) = p;
  }

  float2 pfoF = {0.f, 0.f}; uint2 pfoB = {0u, 0u};   // holds x(t+2) at iter t
  if (sact) {
    if constexpr (!IN_BF16) pfoF = *(const float2*)(xpf + 2 * (size_t)KIN);
    else                    pfoB = *(const uint2*)(xpb + 2 * (size_t)KIN);
  }
  xpf += 3 * (size_t)KIN;                            // points at x(3)
  xpb += 3 * (size_t)KIN;
  __syncthreads();

  // accX_0 = bias + x(0) @ Wih^T  (x(0) frags from A[1].x)
  f32x4 accX[4];
  {
    short8 afx[KCX];
#pragma unroll
    for (int kc = 0; kc < KCX; ++kc)
      afx[kc] = *(const short8*)&AEL(1, l15, kc * 32 + lhi * 8);
#pragma unroll
    for (int gb = 0; gb < 4; ++gb) {
      f32x4 a = {bias4[gb], bias4[gb], bias4[gb], bias4[gb]};
#pragma unroll
      for (int kc = 0; kc < KCX; ++kc)
        a = __builtin_amdgcn_mfma_f32_16x16x32_bf16(afx[kc], wfx[gb][kc], a, 0, 0, 0);
      accX[gb] = a;
    }
  }
  __syncthreads();   // protect A[1].x (just read) from iter-0 writes

  int cur = 0;
  for (int k = 0; k < NCH; ++k) {
    if constexpr (CONS) {
      if (k > 0) {
        const int want = (k + 2 > NCH) ? NCH : (k + 2);
        if (tid == 0) {
          while (__hip_atomic_load(flag, __ATOMIC_ACQUIRE, __HIP_MEMORY_SCOPE_AGENT) < want)
            __builtin_amdgcn_s_sleep(4);
        }
        __syncthreads();
      }
    }

    for (int tt = 0; tt < CH; ++tt) {
      const int t   = k * CH + tt;
      const int nxt = cur ^ 1;

      // issue load of x(t+3); store x(t+2)=pf_old (load retired a step ago)
      float2 pfnF = {0.f, 0.f}; uint2 pfnB = {0u, 0u};
      if (sact) {
        if constexpr (!IN_BF16) {
          pfnF = *(const float2*)xpf;
          *(unsigned int*)&AEL(nxt, 0, scol) =
              (unsigned int)f2bf(pfoF.x) | ((unsigned int)f2bf(pfoF.y) << 16);
        } else {
          pfnB = *(const uint2*)xpb;
          *(uint2*)&AEL(nxt, 0, scol) = pfoB;
        }
      }

      // h(t-1) fragments, then x(t+1) fragments
      short8 afh[KCH];
#pragma unroll
      for (int kc = 0; kc < KCH; ++kc)
        afh[kc] = *(const short8*)&AEL(cur, l15, KIN + kc * 32 + lhi * 8);
      short8 afx[KCX];
#pragma unroll
      for (int kc = 0; kc < KCX; ++kc)
        afx[kc] = *(const short8*)&AEL(cur, l15, kc * 32 + lhi * 8);

      // gates(t) = accX(t) + h(t-1) @ Whh^T
      f32x4 acc[4];
#pragma unroll
      for (int gb = 0; gb < 4; ++gb) {
        f32x4 a = accX[gb];
#pragma unroll
        for (int kc = 0; kc < KCH; ++kc)
          a = __builtin_amdgcn_mfma_f32_16x16x32_bf16(afh[kc], wfh[gb][kc], a, 0, 0, 0);
        acc[gb] = a;
      }

      // fused FC for step t-1 from h(t-1) frags
      f32x4 fs = {fcbias, fcbias, fcbias, fcbias};
      if constexpr (FUSE_FC) {
        if (w < 2 && t > 0) {
#pragma unroll
          for (int kc = 0; kc < 4; ++kc)
            fs = __builtin_amdgcn_mfma_f32_16x16x32_bf16(afh[kc], bfr[kc], fs, 0, 0, 0);
        }
      }

      // accX(t+1) = bias + x(t+1) @ Wih^T  -- independent MFMAs issued here
      // so the gate chain's latency drains under them before EW reads acc.
#pragma unroll
      for (int gb = 0; gb < 4; ++gb) {
        f32x4 a = {bias4[gb], bias4[gb], bias4[gb], bias4[gb]};
#pragma unroll
        for (int kc = 0; kc < KCX; ++kc)
          a = __builtin_amdgcn_mfma_f32_16x16x32_bf16(afx[kc], wfx[gb][kc], a, 0, 0, 0);
        accX[gb] = a;
      }

      // elementwise: the owning lanes (lhi==0) update the single row
      {
        float i_ = sigm(acc[0][0]);
        float f_ = sigm(acc[1][0]);
        float g_ = tanh_f(acc[2][0]);
        float o_ = sigm(acc[3][0]);
        float c_ = f_ * cst + i_ * g_;
        cst = c_;
        float hn = o_ * tanh_f(c_);
        hlast = hn;
        unsigned short hb = f2bf(hn);
        if (own) {
          AEL(nxt, 0, KIN + jcol) = hb;
          if constexpr (WRITE_HOUT) { hp[0] = hb; }
        }
      }
      if constexpr (WRITE_HOUT) hp += H;

      if constexpr (FUSE_FC) {
        if (w < 2 && t > 0 && own)
          fp[(size_t)(t - 1) * O] = fs[0];
      }

      // LDS-only sync: global ops float across steps
      block_sync_lds();
      cur = nxt;
      if constexpr (!IN_BF16) pfoF = pfnF; else pfoB = pfnB;
      if (t <= T - 5) { xpf += KIN; xpb += KIN; }
    }

    if constexpr (PROD) {
      // drain own global stores, barrier, then agent-scope release.
      __builtin_amdgcn_sched_barrier(0);
      asm volatile("s_waitcnt vmcnt(0)" ::: "memory");
      __builtin_amdgcn_s_barrier();
      if (tid == 0)
        __hip_atomic_store(flag, k + 1, __ATOMIC_RELEASE, __HIP_MEMORY_SCOPE_AGENT);
    }
  }

  // ---- tails ----
  if (own) {
    hN[(size_t)bbase * H + jcol] = hlast;
    cN[(size_t)bbase * H + jcol] = cst;
  }
  if constexpr (FUSE_FC) {
    if (w < 2) {   // FC for final step T-1 from h(T-1) frags in A[cur]
      short8 a4[4];
#pragma unroll
      for (int kc = 0; kc < 4; ++kc)
        a4[kc] = *(const short8*)&AEL(cur, l15, KIN + kc * 32 + lhi * 8);
      f32x4 fs = {fcbias, fcbias, fcbias, fcbias};
#pragma unroll
      for (int kc = 0; kc < 4; ++kc)
        fs = __builtin_amdgcn_mfma_f32_16x16x32_bf16(a4[kc], bfr[kc], fs, 0, 0, 0);
      if (own)
        fp[(size_t)(T - 1) * O] = fs[0];
    }
  }
#undef AEL
}

// ---------------------------------------------------------------------------
__global__ __launch_bounds__(512, 4) void lstm_fused(
    const float* __restrict__ x,
    const float* __restrict__ h0, const float* __restrict__ c0,
    const float* __restrict__ Wih0, const float* __restrict__ Whh0,
    const float* __restrict__ bih0, const float* __restrict__ bhh0,
    const float* __restrict__ Wih1, const float* __restrict__ Whh1,
    const float* __restrict__ bih1, const float* __restrict__ bhh1,
    const float* __restrict__ fcw, const float* __restrict__ fcb,
    unsigned short* __restrict__ out0,
    float* __restrict__ out, float* __restrict__ hN, float* __restrict__ cN,
    int* __restrict__ flags)
{
  __shared__ __align__(16) unsigned short Ash[2 * 16 * 264];
  const int bid = blockIdx.x;
  if (bid < NBL) {
    // L0 producer (batch row = bid)
    scan_body<64, false, true, false, true, false>(
        Ash, x, h0, c0, Wih0, Whh0, bih0, bhh0,
        out0, hN, cN, nullptr, nullptr, nullptr,
        flags + bid, bid);
  } else {
    // L1 consumer + fused FC (batch row = bid - NBL)
    const int rb = bid - NBL;
    scan_body<128, true, false, true, false, true>(
        Ash, out0, h0 + B * H, c0 + B * H, Wih1, Whh1, bih1, bhh1,
        nullptr, hN + B * H, cN + B * H, fcw, fcb, out,
        flags + rb, rb);
  }
}

// ---------------------------------------------------------------------------
extern "C" void kernel_launch(void* const* d_in, const int* in_sizes, int n_in,
                              void* d_out, int out_size, void* d_ws, size_t ws_size,
                              hipStream_t stream) {
  (void)in_sizes; (void)n_in; (void)out_size; (void)ws_size;

  const float* x    = (const float*)d_in[0];
  const float* h0   = (const float*)d_in[1];
  const float* c0   = (const float*)d_in[2];
  const float* Wih0 = (const float*)d_in[3];
  const float* Whh0 = (const float*)d_in[4];
  const float* bih0 = (const float*)d_in[5];
  const float* bhh0 = (const float*)d_in[6];
  const float* Wih1 = (const float*)d_in[7];
  const float* Whh1 = (const float*)d_in[8];
  const float* bih1 = (const float*)d_in[9];
  const float* bhh1 = (const float*)d_in[10];
  const float* fcw  = (const float*)d_in[11];
  const float* fcb  = (const float*)d_in[12];

  int*            flags = (int*)d_ws;                             // 256 ints
  unsigned short* out0  = (unsigned short*)((char*)d_ws + 2048);  // bf16 [B,T,H]

  float* out = (float*)d_out;                                     // [B,T,32]
  float* hN  = out + (size_t)B * T * O;                           // [2,B,H]
  float* cN  = hN + (size_t)2 * B * H;                            // [2,B,H]

  hipMemsetAsync(d_ws, 0, 2048, stream);   // reset pipeline flags every launch
  lstm_fused<<<2 * NBL, 512, 0, stream>>>(
      x, h0, c0, Wih0, Whh0, bih0, bhh0, Wih1, Whh1, bih1, bhh1,
      fcw, fcb, out0, out, hN, cN, flags);
}

// Round 10
// 713.812 us; speedup vs baseline: 14.8888x; 14.8888x over previous
//
#include <hip/hip_runtime.h>

// ---------------------------------------------------------------------------
// 2-layer LSTM (B=256,T=1024,in=64,H=128) + FC(128->32), bf16 MFMA.
// Layer-pipelined: 128 blocks = 64 L0 + 64 L1; L1 lags L0 by 2 chunks (CH=8),
// handoff via global out0 + agent-scope release/acquire flags.
// R10: non-recurrent GEMMs chunk-batched with M=timesteps:
//  - accX: per chunk, 2 packed GEMMs (2 batch rows x 8 steps in M=16) compute
//    bias + x@Wih^T for the whole chunk -> spilled bf16 to LDS (same-wave
//    produce/consume, no barrier). Per-step x-MFMAs 16 -> 4 (amortized).
//  - FC: batched at chunk end from an h-history LDS buffer (waves 0-3),
//    1 MFMA/step amortized instead of 4 per step.
// Recurrent h-GEMM unchanged (R6 structure, 766us baseline).
// __launch_bounds__(512,2) (R9 lesson: min-waves=4 forces 64 VGPR -> spills).
// ---------------------------------------------------------------------------

static constexpr int B   = 256;
static constexpr int T   = 1024;
static constexpr int H   = 128;
static constexpr int O   = 32;
static constexpr int R   = 4;          // batch rows per block
static constexpr int NBL = B / R;      // 64 blocks per layer
static constexpr int CH  = 8;          // steps per chunk
static constexpr int NCH = T / CH;     // 128 chunks

// LDS layout (units: shorts)
static constexpr int HROW = H + 8;                 // 136
static constexpr int HB   = 0;                     // Hbuf [2][16][HROW]
static constexpr int HH   = HB + 2 * 16 * HROW;    // Hhist[2][16][HROW]
static constexpr int XB   = HH + 2 * 16 * HROW;    // Xbuf [2][16][XROW<=HROW]
static constexpr int AX   = XB + 2 * 16 * HROW;    // accXL[4][AXB]
static constexpr int AXB  = 8 * 520 + 8;           // 4168 shorts per batch row
static constexpr int LDSN = AX + 4 * AXB;          // 29728 shorts = 59456 B

typedef __attribute__((ext_vector_type(8))) short  short8;
typedef __attribute__((ext_vector_type(4))) float  f32x4;

#define LOG2E 1.4426950408889634f

#if __has_builtin(__builtin_amdgcn_exp2f)
#define EXP2(x) __builtin_amdgcn_exp2f(x)
#else
#define EXP2(x) __expf((x) * 0.69314718056f)
#endif
#if __has_builtin(__builtin_amdgcn_rcpf)
#define RCP(x) __builtin_amdgcn_rcpf(x)
#else
#define RCP(x) (1.0f / (x))
#endif

__device__ __forceinline__ unsigned short f2bf(float f) {
  unsigned int u = __builtin_bit_cast(unsigned int, f);
  u += 0x7fffu + ((u >> 16) & 1u);        // round-to-nearest-even
  return (unsigned short)(u >> 16);
}
__device__ __forceinline__ float bf2f(unsigned short s) {
  return __builtin_bit_cast(float, (unsigned int)s << 16);
}

__device__ __forceinline__ float sigm(float x) {
  return RCP(1.0f + EXP2(-LOG2E * x));
}
__device__ __forceinline__ float tanh_f(float x) {
  return 1.0f - 2.0f * RCP(1.0f + EXP2(2.0f * LOG2E * x));
}

// LDS-only barrier: wait own ds ops, then s_barrier. Global ops float.
__device__ __forceinline__ void block_sync_lds() {
  __builtin_amdgcn_sched_barrier(0);
  asm volatile("s_waitcnt lgkmcnt(0)" ::: "memory");
  __builtin_amdgcn_s_barrier();
  __builtin_amdgcn_sched_barrier(0);
}

// ---------------------------------------------------------------------------
// One layer's full-T scan for R=4 batch rows. 8 waves; wave w owns gate cols
// [w*16,w*16+16) of each gate block (i,f,g,o). Lane owns batch row lhi
// (tile row lhi*4, acc reg 0).
// ---------------------------------------------------------------------------
template <int KIN, bool IN_BF16, bool WRITE_HOUT, bool FUSE_FC, bool PROD, bool CONS>
__device__ __forceinline__ void scan_body(
    unsigned short* __restrict__ S,          // LDS, LDSN shorts
    const void* __restrict__ in_,            // [B,T,KIN] f32 (L0) / bf16 (L1)
    const float* __restrict__ h0,
    const float* __restrict__ c0,
    const float* __restrict__ Wih,           // [4H,KIN]
    const float* __restrict__ Whh,           // [4H,H]
    const float* __restrict__ bih,
    const float* __restrict__ bhh,
    unsigned short* __restrict__ hout,       // bf16 [B,T,H] (L0 only)
    float* __restrict__ hN,
    float* __restrict__ cN,
    const float* __restrict__ Wfc,           // [32,128] (L1 only)
    const float* __restrict__ bfc,
    float* __restrict__ fco,                 // [B,T,32]
    int* __restrict__ flag, const int bbase)
{
  constexpr int KCX  = KIN / 32;             // 2 or 4
  constexpr int KCH  = H / 32;               // 4
  constexpr int XROW = KIN + 8;              // 72 or 136

  const int tid  = threadIdx.x;
  const int w    = tid >> 6;
  const int l    = tid & 63;
  const int l15  = l & 15;
  const int lhi  = l >> 4;
  const int jcol = w * 16 + l15;

  // ---- weight fragments ----
  short8 wfx[4][KCX], wfh[4][KCH];
  float  bias4[4];
#pragma unroll
  for (int gb = 0; gb < 4; ++gb) {
    const int gc = gb * H + jcol;
    const float* wi = Wih + (size_t)gc * KIN;
    const float* wh = Whh + (size_t)gc * H;
#pragma unroll
    for (int kc = 0; kc < KCX; ++kc) {
      const float* s = wi + kc * 32 + lhi * 8;
      float4 a = *(const float4*)s;
      float4 b = *(const float4*)(s + 4);
      short8 v;
      v[0] = (short)f2bf(a.x); v[1] = (short)f2bf(a.y);
      v[2] = (short)f2bf(a.z); v[3] = (short)f2bf(a.w);
      v[4] = (short)f2bf(b.x); v[5] = (short)f2bf(b.y);
      v[6] = (short)f2bf(b.z); v[7] = (short)f2bf(b.w);
      wfx[gb][kc] = v;
    }
#pragma unroll
    for (int kc = 0; kc < KCH; ++kc) {
      const float* s = wh + kc * 32 + lhi * 8;
      float4 a = *(const float4*)s;
      float4 b = *(const float4*)(s + 4);
      short8 v;
      v[0] = (short)f2bf(a.x); v[1] = (short)f2bf(a.y);
      v[2] = (short)f2bf(a.z); v[3] = (short)f2bf(a.w);
      v[4] = (short)f2bf(b.x); v[5] = (short)f2bf(b.y);
      v[6] = (short)f2bf(b.z); v[7] = (short)f2bf(b.w);
      wfh[gb][kc] = v;
    }
    bias4[gb] = bih[gc] + bhh[gc];
  }

  // ---- FC weight fragments (used by waves 0-3; loads always valid) ----
  short8 bfr[4];
  float fcbias = 0.f;
  if constexpr (FUSE_FC) {
    const int oc = (w & 1) * 16 + l15;
#pragma unroll
    for (int kc = 0; kc < 4; ++kc) {
      const float* s = Wfc + (size_t)oc * H + kc * 32 + lhi * 8;
      float4 a = *(const float4*)s;
      float4 b = *(const float4*)(s + 4);
      short8 v;
      v[0] = (short)f2bf(a.x); v[1] = (short)f2bf(a.y);
      v[2] = (short)f2bf(a.z); v[3] = (short)f2bf(a.w);
      v[4] = (short)f2bf(b.x); v[5] = (short)f2bf(b.y);
      v[6] = (short)f2bf(b.z); v[7] = (short)f2bf(b.w);
      bfr[kc] = v;
    }
    fcbias = bfc[oc];
  }

  float cst   = c0[(size_t)(bbase + lhi) * H + jcol];
  float hlast = 0.f;

  const float*          inf = (const float*)in_;
  const unsigned short* inb = (const unsigned short*)in_;

  // ---- X staging lane mapping: (q, row) with b = q*2 + row>>3, ts = row&7 ----
  const int sq  = tid >> 8;                  // GEMM tile 0..1
  const int srw = (tid >> 4) & 15;           // M row 0..15
  const int sb  = bbase + sq * 2 + (srw >> 3);
  const int sts = srw & 7;
  const float*          xsf = inf + ((size_t)sb * T + sts) * KIN + (tid & 15) * 4;
  const unsigned short* xsb = inb + ((size_t)sb * T + sts) * KIN + (tid & 15) * 8;
  const int xdst = XB + (sq * 16 + srw) * XROW +
                   (IN_BF16 ? (tid & 15) * 8 : (tid & 15) * 4);

  unsigned short* hp = nullptr;
  if constexpr (WRITE_HOUT)
    hp = hout + (size_t)(bbase + lhi) * T * H + jcol;

  // ---- zero Hbuf (both buffers) once; garbage M rows stay 0 ----
  for (int i = tid; i < 2 * 16 * HROW / 2; i += 512)
    ((unsigned int*)S)[i] = 0u;
  __syncthreads();

  // ---- consumer: wait for chunks 0,1 before touching in_ ----
  if constexpr (CONS) {
    if (tid == 0) {
      while (__hip_atomic_load(flag, __ATOMIC_ACQUIRE, __HIP_MEMORY_SCOPE_AGENT) < 2)
        __builtin_amdgcn_s_sleep(4);
    }
    __syncthreads();
  }

  // ---- prologue: stage Xbuf chunk 0; h0 -> Hbuf[0] ----
  if constexpr (IN_BF16) {
    uint4 v = *(const uint4*)xsb;
    *(uint4*)&S[xdst] = v;
  } else {
    float4 v = *(const float4*)xsf;
    uint2 p;
    p.x = (unsigned int)f2bf(v.x) | ((unsigned int)f2bf(v.y) << 16);
    p.y = (unsigned int)f2bf(v.z) | ((unsigned int)f2bf(v.w) << 16);
    *(uint2*)&S[xdst] = p;
  }
  S[HB + (lhi * 4) * HROW + jcol] = f2bf(h0[(size_t)(bbase + lhi) * H + jcol]);
  __syncthreads();

  int cur = 0;
  for (int k = 0; k < NCH; ++k) {
    if constexpr (CONS) {
      if (k > 0) {
        const int want = (k + 2 > NCH) ? NCH : (k + 2);
        if (tid == 0) {
          while (__hip_atomic_load(flag, __ATOMIC_ACQUIRE, __HIP_MEMORY_SCOPE_AGENT) < want)
            __builtin_amdgcn_s_sleep(4);
        }
        __syncthreads();
      }
    }

    // ---- accX chunk GEMM: 2 packed GEMMs (2 batch rows x 8 ts in M=16) ----
#pragma unroll
    for (int q = 0; q < 2; ++q) {
      short8 afx[KCX];
#pragma unroll
      for (int kc = 0; kc < KCX; ++kc)
        afx[kc] = *(const short8*)&S[XB + (q * 16 + l15) * XROW + kc * 32 + lhi * 8];
#pragma unroll
      for (int gb = 0; gb < 4; ++gb) {
        f32x4 a = {bias4[gb], bias4[gb], bias4[gb], bias4[gb]};
#pragma unroll
        for (int kc = 0; kc < KCX; ++kc)
          a = __builtin_amdgcn_mfma_f32_16x16x32_bf16(afx[kc], wfx[gb][kc], a, 0, 0, 0);
        const int bb = q * 2 + (lhi >> 1);
#pragma unroll
        for (int r = 0; r < 4; ++r) {
          const int ts = (lhi & 1) * 4 + r;
          S[AX + bb * AXB + ts * 520 + gb * 128 + jcol] = f2bf(a[r]);
        }
      }
    }
    // producer==consumer wave for accXL (col ownership matches) -> no barrier

    // ---- 8 recurrence steps ----
    float4 sF; uint4 sB;                     // staging regs for chunk k+1
    for (int tt = 0; tt < CH; ++tt) {
      if (k + 1 < NCH) {
        if (tt == 0) {
          if constexpr (IN_BF16) sB = *(const uint4*)(xsb + (size_t)(k + 1) * CH * KIN);
          else                   sF = *(const float4*)(xsf + (size_t)(k + 1) * CH * KIN);
        } else if (tt == 1) {    // all waves past GEMM reads (step-0 barrier)
          if constexpr (IN_BF16) {
            *(uint4*)&S[xdst] = sB;
          } else {
            uint2 p;
            p.x = (unsigned int)f2bf(sF.x) | ((unsigned int)f2bf(sF.y) << 16);
            p.y = (unsigned int)f2bf(sF.z) | ((unsigned int)f2bf(sF.w) << 16);
            *(uint2*)&S[xdst] = p;
          }
        }
      }

      // accX for this step (own batch row = lhi)
      float ax[4];
#pragma unroll
      for (int gb = 0; gb < 4; ++gb)
        ax[gb] = bf2f(S[AX + lhi * AXB + tt * 520 + gb * 128 + jcol]);

      // h(t-1) fragments
      short8 afh[KCH];
#pragma unroll
      for (int kc = 0; kc < KCH; ++kc)
        afh[kc] = *(const short8*)&S[HB + (cur * 16 + l15) * HROW + kc * 32 + lhi * 8];

      // gates = accX + h @ Whh^T
      f32x4 acc[4];
#pragma unroll
      for (int gb = 0; gb < 4; ++gb) {
        f32x4 a = {ax[gb], ax[gb], ax[gb], ax[gb]};
#pragma unroll
        for (int kc = 0; kc < KCH; ++kc)
          a = __builtin_amdgcn_mfma_f32_16x16x32_bf16(afh[kc], wfh[gb][kc], a, 0, 0, 0);
        acc[gb] = a;
      }

      const int nxt = cur ^ 1;
      // elementwise (1 row per lane)
      {
        float i_ = sigm(acc[0][0]);
        float f_ = sigm(acc[1][0]);
        float g_ = tanh_f(acc[2][0]);
        float o_ = sigm(acc[3][0]);
        float c_ = f_ * cst + i_ * g_;
        cst = c_;
        float hn = o_ * tanh_f(c_);
        hlast = hn;
        unsigned short hb = f2bf(hn);
        S[HB + (nxt * 16 + lhi * 4) * HROW + jcol] = hb;
        if constexpr (FUSE_FC)
          S[HH + ((lhi >> 1) * 16 + (lhi & 1) * 8 + tt) * HROW + jcol] = hb;
        if constexpr (WRITE_HOUT) { hp[0] = hb; }
      }
      if constexpr (WRITE_HOUT) hp += H;

      block_sync_lds();
      cur = nxt;
    }

    // ---- batched FC for this chunk (h(t) for t in chunk; waves 0-3) ----
    if constexpr (FUSE_FC) {
      if (w < 4) {
        const int q = w >> 1;
        short8 a4[4];
#pragma unroll
        for (int kc = 0; kc < 4; ++kc)
          a4[kc] = *(const short8*)&S[HH + (q * 16 + l15) * HROW + kc * 32 + lhi * 8];
        f32x4 fs = {fcbias, fcbias, fcbias, fcbias};
#pragma unroll
        for (int kc = 0; kc < 4; ++kc)
          fs = __builtin_amdgcn_mfma_f32_16x16x32_bf16(a4[kc], bfr[kc], fs, 0, 0, 0);
        const int brow = bbase + q * 2 + (lhi >> 1);
        const int tb   = k * CH + (lhi & 1) * 4;
#pragma unroll
        for (int r = 0; r < 4; ++r)
          fco[((size_t)brow * T + tb + r) * O + (w & 1) * 16 + l15] = fs[r];
      }
    }

    if constexpr (PROD) {
      __builtin_amdgcn_sched_barrier(0);
      asm volatile("s_waitcnt vmcnt(0)" ::: "memory");
      __builtin_amdgcn_s_barrier();
      if (tid == 0)
        __hip_atomic_store(flag, k + 1, __ATOMIC_RELEASE, __HIP_MEMORY_SCOPE_AGENT);
    }
  }

  // ---- tails ----
  hN[(size_t)(bbase + lhi) * H + jcol] = hlast;
  cN[(size_t)(bbase + lhi) * H + jcol] = cst;
}

// ---------------------------------------------------------------------------
__global__ __launch_bounds__(512, 2) void lstm_fused(
    const float* __restrict__ x,
    const float* __restrict__ h0, const float* __restrict__ c0,
    const float* __restrict__ Wih0, const float* __restrict__ Whh0,
    const float* __restrict__ bih0, const float* __restrict__ bhh0,
    const float* __restrict__ Wih1, const float* __restrict__ Whh1,
    const float* __restrict__ bih1, const float* __restrict__ bhh1,
    const float* __restrict__ fcw, const float* __restrict__ fcb,
    unsigned short* __restrict__ out0,
    float* __restrict__ out, float* __restrict__ hN, float* __restrict__ cN,
    int* __restrict__ flags)
{
  __shared__ __align__(16) unsigned short S[LDSN];   // 59.5 KB
  const int bid = blockIdx.x;
  if (bid < NBL) {
    // L0 producer
    scan_body<64, false, true, false, true, false>(
        S, x, h0, c0, Wih0, Whh0, bih0, bhh0,
        out0, hN, cN, nullptr, nullptr, nullptr,
        flags + bid, bid * R);
  } else {
    // L1 consumer + chunk-batched FC
    const int rb = bid - NBL;
    scan_body<128, true, false, true, false, true>(
        S, out0, h0 + B * H, c0 + B * H, Wih1, Whh1, bih1, bhh1,
        nullptr, hN + B * H, cN + B * H, fcw, fcb, out,
        flags + rb, rb * R);
  }
}

// ---------------------------------------------------------------------------
extern "C" void kernel_launch(void* const* d_in, const int* in_sizes, int n_in,
                              void* d_out, int out_size, void* d_ws, size_t ws_size,
                              hipStream_t stream) {
  (void)in_sizes; (void)n_in; (void)out_size; (void)ws_size;

  const float* x    = (const float*)d_in[0];
  const float* h0   = (const float*)d_in[1];
  const float* c0   = (const float*)d_in[2];
  const float* Wih0 = (const float*)d_in[3];
  const float* Whh0 = (const float*)d_in[4];
  const float* bih0 = (const float*)d_in[5];
  const float* bhh0 = (const float*)d_in[6];
  const float* Wih1 = (const float*)d_in[7];
  const float* Whh1 = (const float*)d_in[8];
  const float* bih1 = (const float*)d_in[9];
  const float* bhh1 = (const float*)d_in[10];
  const float* fcw  = (const float*)d_in[11];
  const float* fcb  = (const float*)d_in[12];

  int*            flags = (int*)d_ws;                             // 64 ints
  unsigned short* out0  = (unsigned short*)((char*)d_ws + 1024);  // bf16 [B,T,H]

  float* out = (float*)d_out;                                     // [B,T,32]
  float* hN  = out + (size_t)B * T * O;                           // [2,B,H]
  float* cN  = hN + (size_t)2 * B * H;                            // [2,B,H]

  hipMemsetAsync(d_ws, 0, 1024, stream);   // reset pipeline flags every launch
  lstm_fused<<<2 * NBL, 512, 0, stream>>>(
      x, h0, c0, Wih0, Whh0, bih0, bhh0, Wih1, Whh1, bih1, bhh1,
      fcw, fcb, out0, out, hN, cN, flags);
}